// Round 17
// baseline (475.664 us; speedup 1.0000x reference)
//
#include <hip/hip_runtime.h>
#include <hip/hip_bf16.h>

// GraphNet: N=50000 nodes, F=128 feats, H=128, MH=256, E=800000 edges
// Inputs FP32; bf16 workspace copies for MFMA; fp32 MFMA accumulation.
// h-space stored PERMUTED (pi: col' = (col%16)*8 + col/16); W2l/W2r/Wm1 k-dim pre-permuted.
// sage1: agg->LDS, barrier, MFMA combine -> h1 (global, pi-space).
// sage2: agg->LDS, combine -> h2 into LDS ONLY (never global), then in-wave PQ GEMM
//        (A from LDS, B=Wm1p from L2) -> PQ [N,512] (col-permuted c*16+nt).
// edge_dot: out[e]=relu(P[src]+Q[dst]).Wm2p + bm2 via dst-CSR per-edge dot (at its
//        L2-miss-path floor ~194MB @3.4TB/s; fp8-P rejected: absmax ~1e-2 > 5.4e-3).
#define NN 50000
#define F 128
#define EE 800000
#define MHD 256

typedef __attribute__((ext_vector_type(8))) short bf16x8;
typedef __attribute__((ext_vector_type(4))) float f32x4;

__device__ __forceinline__ float b2f(unsigned short u) {
    union { unsigned int i; float f; } v; v.i = ((unsigned)u) << 16; return v.f;
}
__device__ __forceinline__ unsigned short f2b(float f) {
    unsigned int x = __float_as_uint(f);
    unsigned int r = x + 0x7fffu + ((x >> 16) & 1u);   // RNE
    return (unsigned short)(r >> 16);
}

// ---------------- combined prep: cast x (6250 blk) | cast+permute W (128 blk) | zero deg (49 blk)
__global__ __launch_bounds__(256) void cast_zero_kernel(
    const float* __restrict__ x,
    const float* __restrict__ W1l, const float* __restrict__ W1r,
    const float* __restrict__ W2l, const float* __restrict__ W2r,
    const float* __restrict__ Wm1,
    unsigned short* __restrict__ xb, unsigned short* __restrict__ wb,
    int* __restrict__ deg) {
    int bid = blockIdx.x;
    if (bid < 6250) {
        int i = (bid * 256 + threadIdx.x) * 4;
        float4 v = *(const float4*)(x + i);
        ushort4 o; o.x = f2b(v.x); o.y = f2b(v.y); o.z = f2b(v.z); o.w = f2b(v.w);
        *(ushort4*)(xb + i) = o;
    } else if (bid < 6378) {
        int i = ((bid - 6250) * 256 + threadIdx.x) * 4;  // 131072 elems / 4
        unsigned short o[4];
        if (i < 32768) {                                 // W1l | W1r straight copy
            const float* p = (i < 16384) ? (W1l + i) : (W1r + (i - 16384));
            float4 v = *(const float4*)p;
            o[0] = f2b(v.x); o[1] = f2b(v.y); o[2] = f2b(v.z); o[3] = f2b(v.w);
        } else if (i < 65536) {                          // W2lp | W2rp (k permuted)
            int local = i - 32768;
            const float* M = (local < 16384) ? W2l : W2r;
            int lm = local & 16383;
            int n = lm >> 7, kp = lm & 127;
#pragma unroll
            for (int t = 0; t < 4; t++) {
                int k = ((kp + t) & 7) * 16 + ((kp + t) >> 3);
                o[t] = f2b(M[n * 128 + k]);
            }
        } else {                                         // Wm1p (k permuted per 128-half)
            int local = i - 65536;
            int n = local >> 8, k2 = local & 255;
            int half = k2 >> 7, kp = k2 & 127;
#pragma unroll
            for (int t = 0; t < 4; t++) {
                int k = half * 128 + ((kp + t) & 7) * 16 + ((kp + t) >> 3);
                o[t] = f2b(Wm1[n * 256 + k]);
            }
        }
        *(ushort4*)(wb + i) = *(ushort4*)o;
    } else {
        int idx = ((bid - 6378) * 256 + threadIdx.x) * 4;
        if (idx < 50016) *(int4*)(deg + idx) = (int4){0, 0, 0, 0};
    }
}

// ---------------- degree histogram straight off edge_index ----------------
__global__ __launch_bounds__(256) void hist_kernel(
    const int* __restrict__ ei, int* __restrict__ deg) {
    __shared__ int isI64;
    if (threadIdx.x == 0) {
        int z = 0;
        for (int i = 1; i < 128; i += 2) z |= ei[i];
        isI64 = (z == 0) ? 1 : 0;
    }
    __syncthreads();
    int e = blockIdx.x * 256 + threadIdx.x;
    if (e >= EE) return;
    int d = isI64 ? (int)((const long long*)ei)[EE + e] : ei[EE + e];
    atomicAdd(&deg[d], 1);
}

// ---------------- device-wide exclusive scan of deg (2 kernels) ----------------
__global__ __launch_bounds__(1024) void scan_p1_kernel(
    const int* __restrict__ deg, int* __restrict__ exloc, int* __restrict__ bsum) {
    __shared__ int part[1024];
    int t = threadIdx.x, gid = blockIdx.x * 1024 + t;
    int v = (gid < NN) ? deg[gid] : 0;
    part[t] = v;
    __syncthreads();
    for (int off = 1; off < 1024; off <<= 1) {
        int u = (t >= off) ? part[t - off] : 0;
        __syncthreads();
        part[t] += u;
        __syncthreads();
    }
    exloc[gid] = part[t] - v;
    if (t == 1023) bsum[blockIdx.x] = part[t];
}

__global__ __launch_bounds__(1024) void scan_p3_kernel(
    const int* __restrict__ exloc, const int* __restrict__ bsum,
    int* __restrict__ rowstart, int* __restrict__ cursor) {
    __shared__ int offs;
    if (threadIdx.x == 0) {
        int s = 0;
        for (int b = 0; b < blockIdx.x; b++) s += bsum[b];
        offs = s;
    }
    __syncthreads();
    int gid = blockIdx.x * 1024 + threadIdx.x;
    if (gid > NN) return;
    if (gid == NN) { rowstart[NN] = EE; return; }
    int r = exloc[gid] + offs;
    rowstart[gid] = r;
    cursor[gid] = r;
}

// ---------------- CSR fill straight off edge_index: one packed 8B store per edge ----------
__global__ __launch_bounds__(256) void fill_kernel(
    const int* __restrict__ ei, int* __restrict__ cursor, int2* __restrict__ nedge) {
    __shared__ int isI64;
    if (threadIdx.x == 0) {
        int z = 0;
        for (int i = 1; i < 128; i += 2) z |= ei[i];
        isI64 = (z == 0) ? 1 : 0;
    }
    __syncthreads();
    int e = blockIdx.x * 256 + threadIdx.x;
    if (e >= EE) return;
    int s, d;
    if (isI64) {
        const long long* e64 = (const long long*)ei;
        s = (int)e64[e];
        d = (int)e64[EE + e];
    } else {
        s = ei[e];
        d = ei[EE + e];
    }
    int p = atomicAdd(&cursor[d], 1);
    nedge[p] = make_int2(s, e);
}

// ---------------- FUSED SAGE layer (+optional in-wave PQ GEMM) ----------------
// Block 256 thr = 4 waves, 64 nodes. Phase A: wave aggregates its 16 nodes (4 groups x 16
// lanes, x8 unroll -> 8x16B loads in flight/lane); mean to LDS (stride 136).
// Phase B: MFMA combine; h (pi-space) -> global (if hout) AND into LDS (if doPQ).
// Phase C (doPQ): in-wave PQ GEMM, A-frags from LDS h2, B=Wm1p, PQ col-permuted stores.
// __syncthreads between ALL LDS producer/consumer phases (R14 lesson: per-thread dataflow
// does NOT order cross-lane LDS). No early return: all waves reach barriers.
__global__ __launch_bounds__(256) void sage_layer_kernel(
    const unsigned short* __restrict__ xin,
    const int2* __restrict__ nedge, const int* __restrict__ rowstart,
    const unsigned short* __restrict__ W1, const unsigned short* __restrict__ W2,
    const float* __restrict__ bias,
    unsigned short* __restrict__ hout,            // may be null (layer 2)
    const unsigned short* __restrict__ wmb,       // Wm1p (doPQ only)
    const float* __restrict__ bm1,                // (doPQ only)
    unsigned short* __restrict__ PQ,              // (doPQ only)
    int doPQ) {
    __shared__ unsigned short lds[4][16][136];
    int wave = threadIdx.x >> 6, lane = threadIdx.x & 63;
    int m0 = (blockIdx.x * 4 + wave) * 16;

    // ---- Phase A: aggregate ----
    int g = lane >> 4, l16 = lane & 15, col8 = l16 * 8;
    for (int batch = 0; batch < 4; batch++) {
        int node = m0 + batch * 4 + g;
        int beg = 0, end = 0;
        if (node < NN) { beg = rowstart[node]; end = rowstart[node + 1]; }
        float a[8] = {0,0,0,0,0,0,0,0};
        float b[8] = {0,0,0,0,0,0,0,0};
        int j = beg;
        for (; j + 7 < end; j += 8) {
            int s0 = nedge[j].x,     s1 = nedge[j + 1].x, s2 = nedge[j + 2].x, s3 = nedge[j + 3].x;
            int s4 = nedge[j + 4].x, s5 = nedge[j + 5].x, s6 = nedge[j + 6].x, s7 = nedge[j + 7].x;
            bf16x8 v0 = *(const bf16x8*)(xin + (size_t)s0 * F + col8);
            bf16x8 v1 = *(const bf16x8*)(xin + (size_t)s1 * F + col8);
            bf16x8 v2 = *(const bf16x8*)(xin + (size_t)s2 * F + col8);
            bf16x8 v3 = *(const bf16x8*)(xin + (size_t)s3 * F + col8);
            bf16x8 v4 = *(const bf16x8*)(xin + (size_t)s4 * F + col8);
            bf16x8 v5 = *(const bf16x8*)(xin + (size_t)s5 * F + col8);
            bf16x8 v6 = *(const bf16x8*)(xin + (size_t)s6 * F + col8);
            bf16x8 v7 = *(const bf16x8*)(xin + (size_t)s7 * F + col8);
            for (int i = 0; i < 8; i++)
                a[i] += (b2f((unsigned short)v0[i]) + b2f((unsigned short)v1[i]))
                      + (b2f((unsigned short)v2[i]) + b2f((unsigned short)v3[i]));
            for (int i = 0; i < 8; i++)
                b[i] += (b2f((unsigned short)v4[i]) + b2f((unsigned short)v5[i]))
                      + (b2f((unsigned short)v6[i]) + b2f((unsigned short)v7[i]));
        }
        for (; j + 3 < end; j += 4) {
            int s0 = nedge[j].x, s1 = nedge[j + 1].x, s2 = nedge[j + 2].x, s3 = nedge[j + 3].x;
            bf16x8 v0 = *(const bf16x8*)(xin + (size_t)s0 * F + col8);
            bf16x8 v1 = *(const bf16x8*)(xin + (size_t)s1 * F + col8);
            bf16x8 v2 = *(const bf16x8*)(xin + (size_t)s2 * F + col8);
            bf16x8 v3 = *(const bf16x8*)(xin + (size_t)s3 * F + col8);
            for (int i = 0; i < 8; i++)
                a[i] += (b2f((unsigned short)v0[i]) + b2f((unsigned short)v1[i]))
                      + (b2f((unsigned short)v2[i]) + b2f((unsigned short)v3[i]));
        }
        for (; j < end; j++) {
            int s0 = nedge[j].x;
            bf16x8 v0 = *(const bf16x8*)(xin + (size_t)s0 * F + col8);
            for (int i = 0; i < 8; i++) a[i] += b2f((unsigned short)v0[i]);
        }
        float inv = 1.0f / fmaxf((float)(end - beg), 1.0f);
        unsigned short o[8];
        for (int i = 0; i < 8; i++) o[i] = f2b((a[i] + b[i]) * inv);
        *(bf16x8*)&lds[wave][batch * 4 + g][col8] = *(bf16x8*)o;
    }
    __syncthreads();   // agg visible to combine

    // ---- Phase B: combine h = relu(agg@W1^T + bias + root@W2^T) ----
    int c = lane & 15, q = lane >> 4;
    f32x4 acc[8];
    for (int nt = 0; nt < 8; nt++) {
        float b = bias[nt * 16 + c];
        acc[nt] = (f32x4){b, b, b, b};
    }
    int mrow = m0 + c; if (mrow > NN - 1) mrow = NN - 1;
    for (int op = 0; op < 2; op++) {
        const unsigned short* W = op ? W2 : W1;
        for (int kb = 0; kb < 4; kb++) {
            bf16x8 a;
            if (op == 0) a = *(const bf16x8*)&lds[wave][c][kb * 32 + q * 8];
            else         a = *(const bf16x8*)(xin + (size_t)mrow * F + kb * 32 + q * 8);
            for (int nt = 0; nt < 8; nt++) {
                bf16x8 b = *(const bf16x8*)(W + (size_t)(nt * 16 + c) * F + kb * 32 + q * 8);
                acc[nt] = __builtin_amdgcn_mfma_f32_16x16x32_bf16(a, b, acc[nt], 0, 0, 0);
            }
        }
    }
    __syncthreads();   // all agg reads done before h overwrites LDS
#pragma unroll
    for (int r = 0; r < 4; r++) {
        int node = m0 + q * 4 + r;
        unsigned short o[8];
#pragma unroll
        for (int nt = 0; nt < 8; nt++) o[nt] = f2b(fmaxf(acc[nt][r], 0.0f));
        if (hout && node < NN)
            *(bf16x8*)(hout + (size_t)node * F + c * 8) = *(bf16x8*)o;
        if (doPQ)
            *(bf16x8*)&lds[wave][q * 4 + r][c * 8] = *(bf16x8*)o;   // pi-space h2 row
    }
    if (!doPQ) return;
    __syncthreads();   // h2 visible to PQ stage

    // ---- Phase C: PQ GEMM (A = LDS h2 pi-space, B = Wm1p k-permuted) ----
    bf16x8 a2[4];
#pragma unroll
    for (int kb = 0; kb < 4; kb++)
        a2[kb] = *(const bf16x8*)&lds[wave][c][kb * 32 + q * 8];
    for (int grp = 0; grp < 4; grp++) {
        int half = grp >> 1, ntBase = (grp & 1) * 8;
        f32x4 pacc[8];
#pragma unroll
        for (int nt = 0; nt < 8; nt++) {
            float b = half ? bm1[(ntBase + nt) * 16 + c] : 0.0f;
            pacc[nt] = (f32x4){b, b, b, b};
        }
#pragma unroll
        for (int kb = 0; kb < 4; kb++) {
#pragma unroll
            for (int nt = 0; nt < 8; nt++) {
                bf16x8 b = *(const bf16x8*)(wmb + (size_t)((ntBase + nt) * 16 + c) * 256 + half * 128 + kb * 32 + q * 8);
                pacc[nt] = __builtin_amdgcn_mfma_f32_16x16x32_bf16(a2[kb], b, pacc[nt], 0, 0, 0);
            }
        }
#pragma unroll
        for (int r = 0; r < 4; r++) {
            int node = m0 + q * 4 + r;
            if (node < NN) {
                unsigned short o[8];
#pragma unroll
                for (int nt = 0; nt < 8; nt++) o[nt] = f2b(pacc[nt][r]);
                *(bf16x8*)(PQ + (size_t)node * 512 + half * 256 + c * 16 + ntBase) = *(bf16x8*)o;
            }
        }
    }
}

// ---------------- edge dot: out[eid] = relu(P[src]+Q[dst]).Wm2p + bm2 ----------------
__global__ __launch_bounds__(256) void edge_dot_kernel(
    const unsigned short* __restrict__ PQ,
    const int2* __restrict__ nedge, const int* __restrict__ rowstart,
    const float* __restrict__ Wm2, const float* __restrict__ bm2,
    float* __restrict__ out) {
    int wave = threadIdx.x >> 6, lane = threadIdx.x & 63;
    int node = blockIdx.x * 4 + wave;
    if (node >= NN) return;
    int g = lane >> 4, l16 = lane & 15;
    int col = l16 * 16;
    float w2f[16], qf[16];
#pragma unroll
    for (int i = 0; i < 16; i++) w2f[i] = Wm2[i * 16 + l16];   // inverse perm gather
    {
        bf16x8 q0 = *(const bf16x8*)(PQ + (size_t)node * 512 + 256 + col);
        bf16x8 q1 = *(const bf16x8*)(PQ + (size_t)node * 512 + 256 + col + 8);
#pragma unroll
        for (int i = 0; i < 8; i++) { qf[i] = b2f((unsigned short)q0[i]); qf[8 + i] = b2f((unsigned short)q1[i]); }
    }
    float b2 = bm2[0];
    int beg = rowstart[node], end = rowstart[node + 1];
    int j = beg + g;
    for (; j + 4 < end; j += 8) {
        int2 e0 = nedge[j], e1 = nedge[j + 4];
        uint4 a0 = *(const uint4*)(PQ + (size_t)e0.x * 512 + col);
        uint4 a1 = *(const uint4*)(PQ + (size_t)e0.x * 512 + col + 8);
        uint4 c0 = *(const uint4*)(PQ + (size_t)e1.x * 512 + col);
        uint4 c1 = *(const uint4*)(PQ + (size_t)e1.x * 512 + col + 8);
        float t0 = 0.f, t1 = 0.f;
        unsigned int w0[8] = {a0.x, a0.y, a0.z, a0.w, a1.x, a1.y, a1.z, a1.w};
        unsigned int w1[8] = {c0.x, c0.y, c0.z, c0.w, c1.x, c1.y, c1.z, c1.w};
#pragma unroll
        for (int i = 0; i < 8; i++) {
            float lo0 = __uint_as_float(w0[i] << 16);
            float hi0 = __uint_as_float(w0[i] & 0xffff0000u);
            float lo1 = __uint_as_float(w1[i] << 16);
            float hi1 = __uint_as_float(w1[i] & 0xffff0000u);
            t0 += fmaxf(lo0 + qf[2 * i], 0.f) * w2f[2 * i]
                + fmaxf(hi0 + qf[2 * i + 1], 0.f) * w2f[2 * i + 1];
            t1 += fmaxf(lo1 + qf[2 * i], 0.f) * w2f[2 * i]
                + fmaxf(hi1 + qf[2 * i + 1], 0.f) * w2f[2 * i + 1];
        }
        t0 += __shfl_xor(t0, 1);  t1 += __shfl_xor(t1, 1);
        t0 += __shfl_xor(t0, 2);  t1 += __shfl_xor(t1, 2);
        t0 += __shfl_xor(t0, 4);  t1 += __shfl_xor(t1, 4);
        t0 += __shfl_xor(t0, 8);  t1 += __shfl_xor(t1, 8);
        if (l16 == 0) { out[e0.y] = t0 + b2; out[e1.y] = t1 + b2; }
    }
    for (; j < end; j += 4) {
        int2 e0 = nedge[j];
        uint4 a0 = *(const uint4*)(PQ + (size_t)e0.x * 512 + col);
        uint4 a1 = *(const uint4*)(PQ + (size_t)e0.x * 512 + col + 8);
        unsigned int w0[8] = {a0.x, a0.y, a0.z, a0.w, a1.x, a1.y, a1.z, a1.w};
        float t = 0.f;
#pragma unroll
        for (int i = 0; i < 8; i++) {
            float lo = __uint_as_float(w0[i] << 16);
            float hi = __uint_as_float(w0[i] & 0xffff0000u);
            t += fmaxf(lo + qf[2 * i], 0.f) * w2f[2 * i]
               + fmaxf(hi + qf[2 * i + 1], 0.f) * w2f[2 * i + 1];
        }
        t += __shfl_xor(t, 1);
        t += __shfl_xor(t, 2);
        t += __shfl_xor(t, 4);
        t += __shfl_xor(t, 8);
        if (l16 == 0) out[e0.y] = t + b2;
    }
}

extern "C" void kernel_launch(void* const* d_in, const int* in_sizes, int n_in,
                              void* d_out, int out_size, void* d_ws, size_t ws_size,
                              hipStream_t stream) {
    const float* x   = (const float*)d_in[0];
    const int*   ei  = (const int*)d_in[1];
    const float* W1l = (const float*)d_in[2];
    const float* b1l = (const float*)d_in[3];
    const float* W1r = (const float*)d_in[4];
    const float* W2l = (const float*)d_in[5];
    const float* b2l = (const float*)d_in[6];
    const float* W2r = (const float*)d_in[7];
    const float* Wm1 = (const float*)d_in[8];
    const float* bm1 = (const float*)d_in[9];
    const float* Wm2 = (const float*)d_in[10];
    const float* bm2 = (const float*)d_in[11];

    char* ws = (char*)d_ws;
    unsigned short* PQ       = (unsigned short*)(ws);                // 51.2MB, overlays xb/h1
    unsigned short* xb       = (unsigned short*)(ws);                // dead before PQ written?
    unsigned short* h1       = (unsigned short*)(ws + 12800000);
    unsigned short* wb       = (unsigned short*)(ws + 51200000);
    int*            deg      = (int*)(ws + 57862144);
    int*            rowstart = (int*)(ws + 58062208);
    int*            cursor   = (int*)(ws + 58262272);
    int2*           nedge    = (int2*)(ws + 58462336);   // 800k x 8B = 6.4MB
    int*            exloc    = (int*)(ws + 77662336);
    int*            bsum     = (int*)(ws + 77867136);
    float*          outp     = (float*)d_out;

    // NOTE: PQ overlays xb (0..12.8M) and h1 (12.8..25.6M) — but sage2 READS xb (no!) —
    // sage2 reads h1 as xin and writes PQ. PQ[0..12.8M) overlays xb (dead after sage2's
    // Phase A/B? sage2 gathers h1, not xb — xb dead after sage1 ✓). PQ[12.8..25.6M)
    // overlays h1, which sage2 is READING while writing PQ → CONFLICT. Move PQ past h1:
    PQ = (unsigned short*)(ws + 83967136);               // separate 51.2MB region

    const unsigned short* w1l_b  = wb;
    const unsigned short* w1r_b  = wb + 16384;
    const unsigned short* w2l_p  = wb + 32768;
    const unsigned short* w2r_p  = wb + 49152;
    const unsigned short* wm1_p  = wb + 65536;

    // prep: combined cast+zero | hist | scan x2 | packed CSR fill (both read ei directly)
    cast_zero_kernel<<<6427, 256, 0, stream>>>(x, W1l, W1r, W2l, W2r, Wm1, xb, wb, deg);
    hist_kernel<<<3125, 256, 0, stream>>>(ei, deg);
    scan_p1_kernel<<<50, 1024, 0, stream>>>(deg, exloc, bsum);
    scan_p3_kernel<<<50, 1024, 0, stream>>>(exloc, bsum, rowstart, cursor);
    fill_kernel<<<3125, 256, 0, stream>>>(ei, cursor, nedge);

    // layer 1: x -> h1 (pi-space)
    sage_layer_kernel<<<782, 256, 0, stream>>>(xb, nedge, rowstart, w1l_b, w1r_b, b1l,
                                               h1, nullptr, nullptr, nullptr, 0);
    // layer 2 + PQ: h1 -> (h2 in LDS only) -> PQ
    sage_layer_kernel<<<782, 256, 0, stream>>>(h1, nedge, rowstart, w2l_p, w2r_p, b2l,
                                               nullptr, wm1_p, bm1, PQ, 1);
    // edge MLP dot
    edge_dot_kernel<<<12500, 256, 0, stream>>>(PQ, nedge, rowstart, Wm2, bm2, outp);
}

// Round 18
// 421.951 us; speedup vs baseline: 1.1273x; 1.1273x over previous
//
#include <hip/hip_runtime.h>
#include <hip/hip_bf16.h>

// GraphNet: N=50000 nodes, F=128 feats, H=128, MH=256, E=800000 edges
// Inputs FP32; bf16 workspace copies for MFMA; fp32 MFMA accumulation.
// h-space stored PERMUTED (pi: col' = (col%16)*8 + col/16); W2l/W2r/Wm1 k-dim pre-permuted.
// SAGE layer FUSED: waves aggregate into LDS (8 loads in flight/lane), __syncthreads,
// MFMA combine. CSR stores (src,eid) PACKED as int2 (one 8B scatter store in fill).
// Edge MLP decomposed: P=h2@W1s^T, Q=h2@W1d^T+bm1 (PQ col-permuted c*16+nt), then
// out[e]=relu(P[src]+Q[dst]).Wm2p + bm2 via per-edge dot.
// NOTE (R17 lesson): keep sage and pq_gemm as SEPARATE kernels — merging them coupled
// register pressure and spilled ~84MB/dispatch to scratch (140us vs 66us).
#define NN 50000
#define F 128
#define EE 800000
#define MHD 256

typedef __attribute__((ext_vector_type(8))) short bf16x8;
typedef __attribute__((ext_vector_type(4))) float f32x4;

__device__ __forceinline__ float b2f(unsigned short u) {
    union { unsigned int i; float f; } v; v.i = ((unsigned)u) << 16; return v.f;
}
__device__ __forceinline__ unsigned short f2b(float f) {
    unsigned int x = __float_as_uint(f);
    unsigned int r = x + 0x7fffu + ((x >> 16) & 1u);   // RNE
    return (unsigned short)(r >> 16);
}

// ---------------- combined prep: cast x (6250 blk) | cast+permute W (128 blk) | zero deg (49 blk)
__global__ __launch_bounds__(256) void cast_zero_kernel(
    const float* __restrict__ x,
    const float* __restrict__ W1l, const float* __restrict__ W1r,
    const float* __restrict__ W2l, const float* __restrict__ W2r,
    const float* __restrict__ Wm1,
    unsigned short* __restrict__ xb, unsigned short* __restrict__ wb,
    int* __restrict__ deg) {
    int bid = blockIdx.x;
    if (bid < 6250) {
        int i = (bid * 256 + threadIdx.x) * 4;
        float4 v = *(const float4*)(x + i);
        ushort4 o; o.x = f2b(v.x); o.y = f2b(v.y); o.z = f2b(v.z); o.w = f2b(v.w);
        *(ushort4*)(xb + i) = o;
    } else if (bid < 6378) {
        int i = ((bid - 6250) * 256 + threadIdx.x) * 4;  // 131072 elems / 4
        unsigned short o[4];
        if (i < 32768) {                                 // W1l | W1r straight copy
            const float* p = (i < 16384) ? (W1l + i) : (W1r + (i - 16384));
            float4 v = *(const float4*)p;
            o[0] = f2b(v.x); o[1] = f2b(v.y); o[2] = f2b(v.z); o[3] = f2b(v.w);
        } else if (i < 65536) {                          // W2lp | W2rp (k permuted)
            int local = i - 32768;
            const float* M = (local < 16384) ? W2l : W2r;
            int lm = local & 16383;
            int n = lm >> 7, kp = lm & 127;
#pragma unroll
            for (int t = 0; t < 4; t++) {
                int k = ((kp + t) & 7) * 16 + ((kp + t) >> 3);
                o[t] = f2b(M[n * 128 + k]);
            }
        } else {                                         // Wm1p (k permuted per 128-half)
            int local = i - 65536;
            int n = local >> 8, k2 = local & 255;
            int half = k2 >> 7, kp = k2 & 127;
#pragma unroll
            for (int t = 0; t < 4; t++) {
                int k = half * 128 + ((kp + t) & 7) * 16 + ((kp + t) >> 3);
                o[t] = f2b(Wm1[n * 256 + k]);
            }
        }
        *(ushort4*)(wb + i) = *(ushort4*)o;
    } else {
        int idx = ((bid - 6378) * 256 + threadIdx.x) * 4;
        if (idx < 50016) *(int4*)(deg + idx) = (int4){0, 0, 0, 0};
    }
}

// ---------------- edge_index canonicalize -> int32 src/dst + degree histogram ----------------
__global__ __launch_bounds__(256) void edge_cvt_hist_kernel(
    const int* __restrict__ ei, int* __restrict__ s32, int* __restrict__ d32,
    int* __restrict__ deg) {
    __shared__ int isI64;
    if (threadIdx.x == 0) {
        int z = 0;
        for (int i = 1; i < 128; i += 2) z |= ei[i];
        isI64 = (z == 0) ? 1 : 0;
    }
    __syncthreads();
    int e = blockIdx.x * 256 + threadIdx.x;
    if (e >= EE) return;
    int s, d;
    if (isI64) {
        const long long* e64 = (const long long*)ei;
        s = (int)e64[e];
        d = (int)e64[EE + e];
    } else {
        s = ei[e];
        d = ei[EE + e];
    }
    s32[e] = s;
    d32[e] = d;
    atomicAdd(&deg[d], 1);
}

// ---------------- device-wide exclusive scan of deg (2 kernels) ----------------
__global__ __launch_bounds__(1024) void scan_p1_kernel(
    const int* __restrict__ deg, int* __restrict__ exloc, int* __restrict__ bsum) {
    __shared__ int part[1024];
    int t = threadIdx.x, gid = blockIdx.x * 1024 + t;
    int v = (gid < NN) ? deg[gid] : 0;
    part[t] = v;
    __syncthreads();
    for (int off = 1; off < 1024; off <<= 1) {
        int u = (t >= off) ? part[t - off] : 0;
        __syncthreads();
        part[t] += u;
        __syncthreads();
    }
    exloc[gid] = part[t] - v;
    if (t == 1023) bsum[blockIdx.x] = part[t];
}

__global__ __launch_bounds__(1024) void scan_p3_kernel(
    const int* __restrict__ exloc, const int* __restrict__ bsum,
    int* __restrict__ rowstart, int* __restrict__ cursor) {
    __shared__ int offs;
    if (threadIdx.x == 0) {
        int s = 0;
        for (int b = 0; b < blockIdx.x; b++) s += bsum[b];
        offs = s;
    }
    __syncthreads();
    int gid = blockIdx.x * 1024 + threadIdx.x;
    if (gid > NN) return;
    if (gid == NN) { rowstart[NN] = EE; return; }
    int r = exloc[gid] + offs;
    rowstart[gid] = r;
    cursor[gid] = r;
}

// ---------------- CSR fill: one packed 8B store per edge ----------------
__global__ __launch_bounds__(256) void fill_kernel(
    const int* __restrict__ s32, const int* __restrict__ d32,
    int* __restrict__ cursor, int2* __restrict__ nedge) {
    int e = blockIdx.x * 256 + threadIdx.x;
    if (e < EE) {
        int p = atomicAdd(&cursor[d32[e]], 1);
        nedge[p] = make_int2(s32[e], e);
    }
}

// ---------------- FUSED SAGE layer: aggregate + combine ----------------
// Block 256 thr = 4 waves, 64 nodes. Phase A: wave aggregates its 16 nodes (4 groups x 16
// lanes), neighbor loop unrolled x8 -> 8x16B loads in flight per lane; mean to LDS
// (stride 136). __syncthreads (cross-lane LDS visibility — R14 bug). Phase B: MFMA
// combine with pi-space 16B-store epilogue. No early return (all waves reach barrier).
__global__ __launch_bounds__(256) void sage_layer_kernel(
    const unsigned short* __restrict__ xin,
    const int2* __restrict__ nedge, const int* __restrict__ rowstart,
    const unsigned short* __restrict__ W1, const unsigned short* __restrict__ W2,
    const float* __restrict__ bias,
    unsigned short* __restrict__ out) {
    __shared__ unsigned short lds[4][16][136];
    int wave = threadIdx.x >> 6, lane = threadIdx.x & 63;
    int m0 = (blockIdx.x * 4 + wave) * 16;

    // ---- Phase A ----
    int g = lane >> 4, l16 = lane & 15, col8 = l16 * 8;
    for (int batch = 0; batch < 4; batch++) {
        int node = m0 + batch * 4 + g;
        int beg = 0, end = 0;
        if (node < NN) { beg = rowstart[node]; end = rowstart[node + 1]; }
        float a[8] = {0,0,0,0,0,0,0,0};
        float b[8] = {0,0,0,0,0,0,0,0};
        int j = beg;
        for (; j + 7 < end; j += 8) {        // 8 loads in flight
            int s0 = nedge[j].x,     s1 = nedge[j + 1].x, s2 = nedge[j + 2].x, s3 = nedge[j + 3].x;
            int s4 = nedge[j + 4].x, s5 = nedge[j + 5].x, s6 = nedge[j + 6].x, s7 = nedge[j + 7].x;
            bf16x8 v0 = *(const bf16x8*)(xin + (size_t)s0 * F + col8);
            bf16x8 v1 = *(const bf16x8*)(xin + (size_t)s1 * F + col8);
            bf16x8 v2 = *(const bf16x8*)(xin + (size_t)s2 * F + col8);
            bf16x8 v3 = *(const bf16x8*)(xin + (size_t)s3 * F + col8);
            bf16x8 v4 = *(const bf16x8*)(xin + (size_t)s4 * F + col8);
            bf16x8 v5 = *(const bf16x8*)(xin + (size_t)s5 * F + col8);
            bf16x8 v6 = *(const bf16x8*)(xin + (size_t)s6 * F + col8);
            bf16x8 v7 = *(const bf16x8*)(xin + (size_t)s7 * F + col8);
            for (int i = 0; i < 8; i++)
                a[i] += (b2f((unsigned short)v0[i]) + b2f((unsigned short)v1[i]))
                      + (b2f((unsigned short)v2[i]) + b2f((unsigned short)v3[i]));
            for (int i = 0; i < 8; i++)
                b[i] += (b2f((unsigned short)v4[i]) + b2f((unsigned short)v5[i]))
                      + (b2f((unsigned short)v6[i]) + b2f((unsigned short)v7[i]));
        }
        for (; j + 3 < end; j += 4) {
            int s0 = nedge[j].x, s1 = nedge[j + 1].x, s2 = nedge[j + 2].x, s3 = nedge[j + 3].x;
            bf16x8 v0 = *(const bf16x8*)(xin + (size_t)s0 * F + col8);
            bf16x8 v1 = *(const bf16x8*)(xin + (size_t)s1 * F + col8);
            bf16x8 v2 = *(const bf16x8*)(xin + (size_t)s2 * F + col8);
            bf16x8 v3 = *(const bf16x8*)(xin + (size_t)s3 * F + col8);
            for (int i = 0; i < 8; i++)
                a[i] += (b2f((unsigned short)v0[i]) + b2f((unsigned short)v1[i]))
                      + (b2f((unsigned short)v2[i]) + b2f((unsigned short)v3[i]));
        }
        for (; j < end; j++) {
            int s0 = nedge[j].x;
            bf16x8 v0 = *(const bf16x8*)(xin + (size_t)s0 * F + col8);
            for (int i = 0; i < 8; i++) a[i] += b2f((unsigned short)v0[i]);
        }
        float inv = 1.0f / fmaxf((float)(end - beg), 1.0f);
        unsigned short o[8];
        for (int i = 0; i < 8; i++) o[i] = f2b((a[i] + b[i]) * inv);
        *(bf16x8*)&lds[wave][batch * 4 + g][col8] = *(bf16x8*)o;
    }
    __syncthreads();   // REQUIRED: cross-lane LDS visibility

    // ---- Phase B ----
    int c = lane & 15, q = lane >> 4;
    f32x4 acc[8];
    for (int nt = 0; nt < 8; nt++) {
        float b = bias[nt * 16 + c];
        acc[nt] = (f32x4){b, b, b, b};
    }
    int mrow = m0 + c; if (mrow > NN - 1) mrow = NN - 1;
    for (int op = 0; op < 2; op++) {
        const unsigned short* W = op ? W2 : W1;
        for (int kb = 0; kb < 4; kb++) {
            bf16x8 a;
            if (op == 0) a = *(const bf16x8*)&lds[wave][c][kb * 32 + q * 8];
            else         a = *(const bf16x8*)(xin + (size_t)mrow * F + kb * 32 + q * 8);
            for (int nt = 0; nt < 8; nt++) {
                bf16x8 b = *(const bf16x8*)(W + (size_t)(nt * 16 + c) * F + kb * 32 + q * 8);
                acc[nt] = __builtin_amdgcn_mfma_f32_16x16x32_bf16(a, b, acc[nt], 0, 0, 0);
            }
        }
    }
#pragma unroll
    for (int r = 0; r < 4; r++) {
        int node = m0 + q * 4 + r;
        if (node < NN) {
            unsigned short o[8];
#pragma unroll
            for (int nt = 0; nt < 8; nt++) o[nt] = f2b(fmaxf(acc[nt][r], 0.0f));
            *(bf16x8*)(out + (size_t)node * F + c * 8) = *(bf16x8*)o;
        }
    }
}

// ---------------- PQ GEMM (wave-split N, permuted out cols): PQ[n] bf16 [N,512] ----------
__global__ __launch_bounds__(256) void pq_gemm_kernel(
    const unsigned short* __restrict__ h,
    const unsigned short* __restrict__ wmb,
    const float* __restrict__ bm1,
    unsigned short* __restrict__ PQ) {
    int wave = threadIdx.x >> 6, lane = threadIdx.x & 63;
    int c = lane & 15, q = lane >> 4;
    int half = wave >> 1, ntBase = (wave & 1) * 8;
    int m0 = blockIdx.x * 16;
    int mrow = m0 + c; if (mrow > NN - 1) mrow = NN - 1;
    bf16x8 a[4];
#pragma unroll
    for (int kb = 0; kb < 4; kb++)
        a[kb] = *(const bf16x8*)(h + (size_t)mrow * F + kb * 32 + q * 8);
    f32x4 acc[8];
#pragma unroll
    for (int nt = 0; nt < 8; nt++) {
        float b = half ? bm1[(ntBase + nt) * 16 + c] : 0.0f;
        acc[nt] = (f32x4){b, b, b, b};
    }
#pragma unroll
    for (int kb = 0; kb < 4; kb++) {
#pragma unroll
        for (int nt = 0; nt < 8; nt++) {
            bf16x8 b = *(const bf16x8*)(wmb + (size_t)((ntBase + nt) * 16 + c) * 256 + half * 128 + kb * 32 + q * 8);
            acc[nt] = __builtin_amdgcn_mfma_f32_16x16x32_bf16(a[kb], b, acc[nt], 0, 0, 0);
        }
    }
#pragma unroll
    for (int r = 0; r < 4; r++) {
        int node = m0 + q * 4 + r;
        if (node < NN) {
            unsigned short o[8];
#pragma unroll
            for (int nt = 0; nt < 8; nt++) o[nt] = f2b(acc[nt][r]);
            *(bf16x8*)(PQ + (size_t)node * 512 + half * 256 + c * 16 + ntBase) = *(bf16x8*)o;
        }
    }
}

// ---------------- edge dot: out[eid] = relu(P[src]+Q[dst]).Wm2p + bm2 ----------------
// One wave per dst node; 16 lanes/edge, x2 unroll (8 edges in flight/wave); packed
// (src,eid) int2 loads; bf16 unpack via dword shift/mask.
__global__ __launch_bounds__(256) void edge_dot_kernel(
    const unsigned short* __restrict__ PQ,
    const int2* __restrict__ nedge, const int* __restrict__ rowstart,
    const float* __restrict__ Wm2, const float* __restrict__ bm2,
    float* __restrict__ out) {
    int wave = threadIdx.x >> 6, lane = threadIdx.x & 63;
    int node = blockIdx.x * 4 + wave;
    if (node >= NN) return;
    int g = lane >> 4, l16 = lane & 15;
    int col = l16 * 16;
    float w2f[16], qf[16];
#pragma unroll
    for (int i = 0; i < 16; i++) w2f[i] = Wm2[i * 16 + l16];   // inverse perm gather
    {
        bf16x8 q0 = *(const bf16x8*)(PQ + (size_t)node * 512 + 256 + col);
        bf16x8 q1 = *(const bf16x8*)(PQ + (size_t)node * 512 + 256 + col + 8);
#pragma unroll
        for (int i = 0; i < 8; i++) { qf[i] = b2f((unsigned short)q0[i]); qf[8 + i] = b2f((unsigned short)q1[i]); }
    }
    float b2 = bm2[0];
    int beg = rowstart[node], end = rowstart[node + 1];
    int j = beg + g;
    for (; j + 4 < end; j += 8) {
        int2 e0 = nedge[j], e1 = nedge[j + 4];
        uint4 a0 = *(const uint4*)(PQ + (size_t)e0.x * 512 + col);
        uint4 a1 = *(const uint4*)(PQ + (size_t)e0.x * 512 + col + 8);
        uint4 c0 = *(const uint4*)(PQ + (size_t)e1.x * 512 + col);
        uint4 c1 = *(const uint4*)(PQ + (size_t)e1.x * 512 + col + 8);
        float t0 = 0.f, t1 = 0.f;
        unsigned int w0[8] = {a0.x, a0.y, a0.z, a0.w, a1.x, a1.y, a1.z, a1.w};
        unsigned int w1[8] = {c0.x, c0.y, c0.z, c0.w, c1.x, c1.y, c1.z, c1.w};
#pragma unroll
        for (int i = 0; i < 8; i++) {
            float lo0 = __uint_as_float(w0[i] << 16);
            float hi0 = __uint_as_float(w0[i] & 0xffff0000u);
            float lo1 = __uint_as_float(w1[i] << 16);
            float hi1 = __uint_as_float(w1[i] & 0xffff0000u);
            t0 += fmaxf(lo0 + qf[2 * i], 0.f) * w2f[2 * i]
                + fmaxf(hi0 + qf[2 * i + 1], 0.f) * w2f[2 * i + 1];
            t1 += fmaxf(lo1 + qf[2 * i], 0.f) * w2f[2 * i]
                + fmaxf(hi1 + qf[2 * i + 1], 0.f) * w2f[2 * i + 1];
        }
        t0 += __shfl_xor(t0, 1);  t1 += __shfl_xor(t1, 1);
        t0 += __shfl_xor(t0, 2);  t1 += __shfl_xor(t1, 2);
        t0 += __shfl_xor(t0, 4);  t1 += __shfl_xor(t1, 4);
        t0 += __shfl_xor(t0, 8);  t1 += __shfl_xor(t1, 8);
        if (l16 == 0) { out[e0.y] = t0 + b2; out[e1.y] = t1 + b2; }
    }
    for (; j < end; j += 4) {
        int2 e0 = nedge[j];
        uint4 a0 = *(const uint4*)(PQ + (size_t)e0.x * 512 + col);
        uint4 a1 = *(const uint4*)(PQ + (size_t)e0.x * 512 + col + 8);
        unsigned int w0[8] = {a0.x, a0.y, a0.z, a0.w, a1.x, a1.y, a1.z, a1.w};
        float t = 0.f;
#pragma unroll
        for (int i = 0; i < 8; i++) {
            float lo = __uint_as_float(w0[i] << 16);
            float hi = __uint_as_float(w0[i] & 0xffff0000u);
            t += fmaxf(lo + qf[2 * i], 0.f) * w2f[2 * i]
               + fmaxf(hi + qf[2 * i + 1], 0.f) * w2f[2 * i + 1];
        }
        t += __shfl_xor(t, 1);
        t += __shfl_xor(t, 2);
        t += __shfl_xor(t, 4);
        t += __shfl_xor(t, 8);
        if (l16 == 0) out[e0.y] = t + b2;
    }
}

extern "C" void kernel_launch(void* const* d_in, const int* in_sizes, int n_in,
                              void* d_out, int out_size, void* d_ws, size_t ws_size,
                              hipStream_t stream) {
    const float* x   = (const float*)d_in[0];
    const int*   ei  = (const int*)d_in[1];
    const float* W1l = (const float*)d_in[2];
    const float* b1l = (const float*)d_in[3];
    const float* W1r = (const float*)d_in[4];
    const float* W2l = (const float*)d_in[5];
    const float* b2l = (const float*)d_in[6];
    const float* W2r = (const float*)d_in[7];
    const float* Wm1 = (const float*)d_in[8];
    const float* bm1 = (const float*)d_in[9];
    const float* Wm2 = (const float*)d_in[10];
    const float* bm2 = (const float*)d_in[11];

    char* ws = (char*)d_ws;
    unsigned short* PQ       = (unsigned short*)(ws);                // 51.2MB, overlays xb/h1
    unsigned short* xb       = (unsigned short*)(ws);
    unsigned short* h1       = (unsigned short*)(ws + 12800000);
    unsigned short* wb       = (unsigned short*)(ws + 51200000);
    int*            s32      = (int*)(ws + 51462144);
    int*            d32      = (int*)(ws + 54662144);
    int*            deg      = (int*)(ws + 57862144);
    int*            rowstart = (int*)(ws + 58062208);
    int*            cursor   = (int*)(ws + 58262272);
    int2*           nedge    = (int2*)(ws + 58462336);   // 800k x 8B = 6.4MB
    unsigned short* h2       = (unsigned short*)(ws + 64862336);
    int*            exloc    = (int*)(ws + 77662336);
    int*            bsum     = (int*)(ws + 77867136);
    float*          outp     = (float*)d_out;

    const unsigned short* w1l_b  = wb;
    const unsigned short* w1r_b  = wb + 16384;
    const unsigned short* w2l_p  = wb + 32768;
    const unsigned short* w2r_p  = wb + 49152;
    const unsigned short* wm1_p  = wb + 65536;

    // prep: combined cast+zero | cvt+hist | scan x2 | packed CSR fill
    cast_zero_kernel<<<6427, 256, 0, stream>>>(x, W1l, W1r, W2l, W2r, Wm1, xb, wb, deg);
    edge_cvt_hist_kernel<<<3125, 256, 0, stream>>>(ei, s32, d32, deg);
    scan_p1_kernel<<<50, 1024, 0, stream>>>(deg, exloc, bsum);
    scan_p3_kernel<<<50, 1024, 0, stream>>>(exloc, bsum, rowstart, cursor);
    fill_kernel<<<3125, 256, 0, stream>>>(s32, d32, cursor, nedge);

    // layer 1 (fused agg+combine; x unpermuted in, h1 pi-space out)
    sage_layer_kernel<<<782, 256, 0, stream>>>(xb, nedge, rowstart, w1l_b, w1r_b, b1l, h1);
    // layer 2 (h1 pi-space in with k-permuted W2, h2 pi-space out)
    sage_layer_kernel<<<782, 256, 0, stream>>>(h1, nedge, rowstart, w2l_p, w2r_p, b2l, h2);
    // edge MLP (decomposed; Wm1 k-permuted to match h2 pi-space)
    pq_gemm_kernel<<<3125, 256, 0, stream>>>(h2, wm1_p, bm1, PQ);
    edge_dot_kernel<<<12500, 256, 0, stream>>>(PQ, nedge, rowstart, Wm2, bm2, outp);
}